// Round 1
// baseline (83.530 us; speedup 1.0000x reference)
//
#include <hip/hip_runtime.h>

#define BATCH   2048
#define IN_DIM  16384
#define OUT_DIM 16384
#define NGATES  16

// COEFF[16][4] from the reference, hard-coded.
__constant__ float c_coeff[NGATES][4] = {
    {0, 0, 0, 0},  {0, 0, 0, 1},  {0, 1, 0, -1}, {0, 1, 0, 0},
    {0, 0, 1, -1}, {0, 0, 1, 0},  {0, 1, 1, -2}, {0, 1, 1, -1},
    {1, -1, -1, 1},{1, -1, -1, 2},{1, 0, -1, 0}, {1, 0, -1, 1},
    {1, -1, 0, 0}, {1, -1, 0, 1}, {1, 0, 0, -1}, {1, 0, 0, 0}
};

// Kernel 1: per output column j, compute W[j] = softmax(weights[j,:]) @ COEFF
// and pack the gather indices. Output: Wp[j] = float4(w0,w1,w2,w3), Ip[j] = int2(ia,ib).
__global__ __launch_bounds__(256) void prep_kernel(
    const float* __restrict__ weights,
    const int*   __restrict__ idx_a,
    const int*   __restrict__ idx_b,
    float4*      __restrict__ Wp,
    int2*        __restrict__ Ip)
{
    int j = blockIdx.x * blockDim.x + threadIdx.x;
    if (j >= OUT_DIM) return;

    const float4* wrow = reinterpret_cast<const float4*>(weights + (size_t)j * NGATES);
    float v[NGATES];
    float4 q0 = wrow[0], q1 = wrow[1], q2 = wrow[2], q3 = wrow[3];
    v[0]=q0.x; v[1]=q0.y; v[2]=q0.z; v[3]=q0.w;
    v[4]=q1.x; v[5]=q1.y; v[6]=q1.z; v[7]=q1.w;
    v[8]=q2.x; v[9]=q2.y; v[10]=q2.z; v[11]=q2.w;
    v[12]=q3.x; v[13]=q3.y; v[14]=q3.z; v[15]=q3.w;

    float m = v[0];
#pragma unroll
    for (int g = 1; g < NGATES; ++g) m = fmaxf(m, v[g]);
    float s = 0.f;
#pragma unroll
    for (int g = 0; g < NGATES; ++g) { v[g] = expf(v[g] - m); s += v[g]; }
    float inv = 1.0f / s;

    float c0 = 0.f, c1 = 0.f, c2 = 0.f, c3 = 0.f;
#pragma unroll
    for (int g = 0; g < NGATES; ++g) {
        c0 += v[g] * c_coeff[g][0];
        c1 += v[g] * c_coeff[g][1];
        c2 += v[g] * c_coeff[g][2];
        c3 += v[g] * c_coeff[g][3];
    }
    Wp[j] = make_float4(c0 * inv, c1 * inv, c2 * inv, c3 * inv);
    Ip[j] = make_int2(idx_a[j], idx_b[j]);
}

// Kernel 2: one block per batch row. Stage x[i,:] (64 KB) in LDS, then each
// thread produces 4 consecutive outputs per iteration with LDS gathers.
__global__ __launch_bounds__(256) void logic_row_kernel(
    const float*  __restrict__ x,
    const float4* __restrict__ Wp,
    const int2*   __restrict__ Ip,
    float*        __restrict__ out)
{
    __shared__ float row[IN_DIM];   // 64 KB

    const int i = blockIdx.x;
    const float4* xr = reinterpret_cast<const float4*>(x + (size_t)i * IN_DIM);
    float4* rr = reinterpret_cast<float4*>(row);
#pragma unroll
    for (int t = threadIdx.x; t < IN_DIM / 4; t += 256) rr[t] = xr[t];
    __syncthreads();

    float4* o4 = reinterpret_cast<float4*>(out + (size_t)i * OUT_DIM);
    const int4* ip4 = reinterpret_cast<const int4*>(Ip);

    for (int j4 = threadIdx.x; j4 < OUT_DIM / 4; j4 += 256) {
        const int j = j4 * 4;
        float4 w0 = Wp[j], w1 = Wp[j + 1], w2 = Wp[j + 2], w3 = Wp[j + 3];
        int4 ii0 = ip4[j4 * 2];       // (ia0, ib0, ia1, ib1)
        int4 ii1 = ip4[j4 * 2 + 1];   // (ia2, ib2, ia3, ib3)

        float a0 = row[ii0.x], b0 = row[ii0.y];
        float a1 = row[ii0.z], b1 = row[ii0.w];
        float a2 = row[ii1.x], b2 = row[ii1.y];
        float a3 = row[ii1.z], b3 = row[ii1.w];

        float4 r;
        r.x = w0.x + w0.y * a0 + w0.z * b0 + w0.w * (a0 * b0);
        r.y = w1.x + w1.y * a1 + w1.z * b1 + w1.w * (a1 * b1);
        r.z = w2.x + w2.y * a2 + w2.z * b2 + w2.w * (a2 * b2);
        r.w = w3.x + w3.y * a3 + w3.z * b3 + w3.w * (a3 * b3);
        o4[j4] = r;
    }
}

extern "C" void kernel_launch(void* const* d_in, const int* in_sizes, int n_in,
                              void* d_out, int out_size, void* d_ws, size_t ws_size,
                              hipStream_t stream) {
    const float* x       = (const float*)d_in[0];
    const float* weights = (const float*)d_in[1];
    const int*   idx_a   = (const int*)d_in[2];
    const int*   idx_b   = (const int*)d_in[3];
    float* out = (float*)d_out;

    // Workspace layout: Wp (OUT_DIM float4 = 256 KB), Ip (OUT_DIM int2 = 128 KB)
    float4* Wp = (float4*)d_ws;
    int2*   Ip = (int2*)((char*)d_ws + (size_t)OUT_DIM * sizeof(float4));

    prep_kernel<<<(OUT_DIM + 255) / 256, 256, 0, stream>>>(weights, idx_a, idx_b, Wp, Ip);
    logic_row_kernel<<<BATCH, 256, 0, stream>>>(x, Wp, Ip, out);
}

// Round 2
// 66.312 us; speedup vs baseline: 1.2597x; 1.2597x over previous
//
#include <hip/hip_runtime.h>

#define BATCH   2048
#define IN_DIM  16384
#define OUT_DIM 16384
#define NGATES  16

typedef float f32x4 __attribute__((ext_vector_type(4)));

// COEFF[16][4] from the reference, hard-coded.
__constant__ float c_coeff[NGATES][4] = {
    {0, 0, 0, 0},  {0, 0, 0, 1},  {0, 1, 0, -1}, {0, 1, 0, 0},
    {0, 0, 1, -1}, {0, 0, 1, 0},  {0, 1, 1, -2}, {0, 1, 1, -1},
    {1, -1, -1, 1},{1, -1, -1, 2},{1, 0, -1, 0}, {1, 0, -1, 1},
    {1, -1, 0, 0}, {1, -1, 0, 1}, {1, 0, 0, -1}, {1, 0, 0, 0}
};

// Kernel 1: per output column j, fold softmax(weights[j,:]) @ COEFF into W[j]
// (float4) and pack gather indices (int2).
__global__ __launch_bounds__(256) void prep_kernel(
    const float* __restrict__ weights,
    const int*   __restrict__ idx_a,
    const int*   __restrict__ idx_b,
    float4*      __restrict__ Wp,
    int2*        __restrict__ Ip)
{
    int j = blockIdx.x * blockDim.x + threadIdx.x;
    if (j >= OUT_DIM) return;

    const float4* wrow = reinterpret_cast<const float4*>(weights + (size_t)j * NGATES);
    float v[NGATES];
    float4 q0 = wrow[0], q1 = wrow[1], q2 = wrow[2], q3 = wrow[3];
    v[0]=q0.x; v[1]=q0.y; v[2]=q0.z; v[3]=q0.w;
    v[4]=q1.x; v[5]=q1.y; v[6]=q1.z; v[7]=q1.w;
    v[8]=q2.x; v[9]=q2.y; v[10]=q2.z; v[11]=q2.w;
    v[12]=q3.x; v[13]=q3.y; v[14]=q3.z; v[15]=q3.w;

    float m = v[0];
#pragma unroll
    for (int g = 1; g < NGATES; ++g) m = fmaxf(m, v[g]);
    float s = 0.f;
#pragma unroll
    for (int g = 0; g < NGATES; ++g) { v[g] = expf(v[g] - m); s += v[g]; }
    float inv = 1.0f / s;

    float c0 = 0.f, c1 = 0.f, c2 = 0.f, c3 = 0.f;
#pragma unroll
    for (int g = 0; g < NGATES; ++g) {
        c0 += v[g] * c_coeff[g][0];
        c1 += v[g] * c_coeff[g][1];
        c2 += v[g] * c_coeff[g][2];
        c3 += v[g] * c_coeff[g][3];
    }
    Wp[j] = make_float4(c0 * inv, c1 * inv, c2 * inv, c3 * inv);
    Ip[j] = make_int2(idx_a[j], idx_b[j]);
}

// Kernel 2: one block (512 threads) per batch row. Stage x[i,:] (64 KB) in
// LDS with coalesced float4 loads, then each thread produces 4 consecutive
// outputs per iteration via LDS gathers. 2 blocks/CU resident (128 KB LDS),
// 16 waves/CU. Nontemporal stores keep `out` from evicting x in L2/L3.
__global__ __launch_bounds__(512) void logic_row_kernel(
    const float*  __restrict__ x,
    const float4* __restrict__ Wp,
    const int2*   __restrict__ Ip,
    float*        __restrict__ out)
{
    __shared__ float row[IN_DIM];   // 64 KB

    const int i = blockIdx.x;
    const float4* xr = reinterpret_cast<const float4*>(x + (size_t)i * IN_DIM);
    float4* rr = reinterpret_cast<float4*>(row);
#pragma unroll
    for (int k = 0; k < IN_DIM / 4 / 512; ++k)       // 8 coalesced float4 loads
        rr[threadIdx.x + k * 512] = xr[threadIdx.x + k * 512];
    __syncthreads();

    f32x4* o4 = reinterpret_cast<f32x4*>(out + (size_t)i * OUT_DIM);
    const int4* ip4 = reinterpret_cast<const int4*>(Ip);

#pragma unroll 2
    for (int k = 0; k < OUT_DIM / 4 / 512; ++k) {    // 8 iterations
        const int j4 = threadIdx.x + k * 512;
        const int j = j4 * 4;
        float4 w0 = Wp[j], w1 = Wp[j + 1], w2 = Wp[j + 2], w3 = Wp[j + 3];
        int4 ii0 = ip4[j4 * 2];       // (ia0, ib0, ia1, ib1)
        int4 ii1 = ip4[j4 * 2 + 1];   // (ia2, ib2, ia3, ib3)

        float a0 = row[ii0.x], b0 = row[ii0.y];
        float a1 = row[ii0.z], b1 = row[ii0.w];
        float a2 = row[ii1.x], b2 = row[ii1.y];
        float a3 = row[ii1.z], b3 = row[ii1.w];

        f32x4 r;
        r.x = w0.x + w0.y * a0 + w0.z * b0 + w0.w * (a0 * b0);
        r.y = w1.x + w1.y * a1 + w1.z * b1 + w1.w * (a1 * b1);
        r.z = w2.x + w2.y * a2 + w2.z * b2 + w2.w * (a2 * b2);
        r.w = w3.x + w3.y * a3 + w3.z * b3 + w3.w * (a3 * b3);
        __builtin_nontemporal_store(r, &o4[j4]);
    }
}

extern "C" void kernel_launch(void* const* d_in, const int* in_sizes, int n_in,
                              void* d_out, int out_size, void* d_ws, size_t ws_size,
                              hipStream_t stream) {
    const float* x       = (const float*)d_in[0];
    const float* weights = (const float*)d_in[1];
    const int*   idx_a   = (const int*)d_in[2];
    const int*   idx_b   = (const int*)d_in[3];
    float* out = (float*)d_out;

    // Workspace layout: Wp (OUT_DIM float4 = 256 KB), Ip (OUT_DIM int2 = 128 KB)
    float4* Wp = (float4*)d_ws;
    int2*   Ip = (int2*)((char*)d_ws + (size_t)OUT_DIM * sizeof(float4));

    prep_kernel<<<(OUT_DIM + 255) / 256, 256, 0, stream>>>(weights, idx_a, idx_b, Wp, Ip);
    logic_row_kernel<<<BATCH, 512, 0, stream>>>(x, Wp, Ip, out);
}

// Round 3
// 59.401 us; speedup vs baseline: 1.4062x; 1.1163x over previous
//
#include <hip/hip_runtime.h>

#define BATCH   2048
#define IN_DIM  16384
#define OUT_DIM 16384
#define NGATES  16

typedef float f32x4 __attribute__((ext_vector_type(4)));

// COEFF[16][4] from the reference, hard-coded.
__constant__ float c_coeff[NGATES][4] = {
    {0, 0, 0, 0},  {0, 0, 0, 1},  {0, 1, 0, -1}, {0, 1, 0, 0},
    {0, 0, 1, -1}, {0, 0, 1, 0},  {0, 1, 1, -2}, {0, 1, 1, -1},
    {1, -1, -1, 1},{1, -1, -1, 2},{1, 0, -1, 0}, {1, 0, -1, 1},
    {1, -1, 0, 0}, {1, -1, 0, 1}, {1, 0, 0, -1}, {1, 0, 0, 0}
};

// Kernel 1: per output column j, fold softmax(weights[j,:]) @ COEFF into W[j]
// (float4) and pack both gather indices into one uint32 (ia | ib<<16).
__global__ __launch_bounds__(256) void prep_kernel(
    const float* __restrict__ weights,
    const int*   __restrict__ idx_a,
    const int*   __restrict__ idx_b,
    float4*      __restrict__ Wp,
    unsigned*    __restrict__ Ipk)
{
    int j = blockIdx.x * blockDim.x + threadIdx.x;
    if (j >= OUT_DIM) return;

    const float4* wrow = reinterpret_cast<const float4*>(weights + (size_t)j * NGATES);
    float v[NGATES];
    float4 q0 = wrow[0], q1 = wrow[1], q2 = wrow[2], q3 = wrow[3];
    v[0]=q0.x; v[1]=q0.y; v[2]=q0.z; v[3]=q0.w;
    v[4]=q1.x; v[5]=q1.y; v[6]=q1.z; v[7]=q1.w;
    v[8]=q2.x; v[9]=q2.y; v[10]=q2.z; v[11]=q2.w;
    v[12]=q3.x; v[13]=q3.y; v[14]=q3.z; v[15]=q3.w;

    float m = v[0];
#pragma unroll
    for (int g = 1; g < NGATES; ++g) m = fmaxf(m, v[g]);
    float s = 0.f;
#pragma unroll
    for (int g = 0; g < NGATES; ++g) { v[g] = expf(v[g] - m); s += v[g]; }
    float inv = 1.0f / s;

    float c0 = 0.f, c1 = 0.f, c2 = 0.f, c3 = 0.f;
#pragma unroll
    for (int g = 0; g < NGATES; ++g) {
        c0 += v[g] * c_coeff[g][0];
        c1 += v[g] * c_coeff[g][1];
        c2 += v[g] * c_coeff[g][2];
        c3 += v[g] * c_coeff[g][3];
    }
    Wp[j] = make_float4(c0 * inv, c1 * inv, c2 * inv, c3 * inv);
    Ipk[j] = (unsigned)idx_a[j] | ((unsigned)idx_b[j] << 16);   // both < 16384
}

// Kernel 2: one block (1024 threads) per batch row. Stage x[i,:] (64 KB) in
// LDS, then each thread produces 16 outputs (4 iters x 4). 64 KB LDS ->
// 2 blocks/CU resident = 32 waves/CU (100% occupancy). Fully unrolled so the
// compiler hoists W/idx loads; nontemporal stores keep `out` out of L3.
__global__ __launch_bounds__(1024) void logic_row_kernel(
    const float*  __restrict__ x,
    const float4* __restrict__ Wp,
    const uint4*  __restrict__ Ipk4,
    float*        __restrict__ out)
{
    __shared__ float row[IN_DIM];   // 64 KB

    const int i = blockIdx.x;
    const float4* xr = reinterpret_cast<const float4*>(x + (size_t)i * IN_DIM);
    float4* rr = reinterpret_cast<float4*>(row);
#pragma unroll
    for (int k = 0; k < IN_DIM / 4 / 1024; ++k)      // 4 coalesced float4 loads
        rr[threadIdx.x + k * 1024] = xr[threadIdx.x + k * 1024];
    __syncthreads();

    f32x4* o4 = reinterpret_cast<f32x4*>(out + (size_t)i * OUT_DIM);

#pragma unroll
    for (int k = 0; k < OUT_DIM / 4 / 1024; ++k) {   // 4 iterations
        const int j4 = threadIdx.x + k * 1024;
        const int j = j4 * 4;
        float4 w0 = Wp[j], w1 = Wp[j + 1], w2 = Wp[j + 2], w3 = Wp[j + 3];
        uint4 ii = Ipk4[j4];                         // 4 packed (ia|ib<<16)

        float a0 = row[ii.x & 0xFFFFu], b0 = row[ii.x >> 16];
        float a1 = row[ii.y & 0xFFFFu], b1 = row[ii.y >> 16];
        float a2 = row[ii.z & 0xFFFFu], b2 = row[ii.z >> 16];
        float a3 = row[ii.w & 0xFFFFu], b3 = row[ii.w >> 16];

        f32x4 r;
        r.x = w0.x + w0.y * a0 + w0.z * b0 + w0.w * (a0 * b0);
        r.y = w1.x + w1.y * a1 + w1.z * b1 + w1.w * (a1 * b1);
        r.z = w2.x + w2.y * a2 + w2.z * b2 + w2.w * (a2 * b2);
        r.w = w3.x + w3.y * a3 + w3.z * b3 + w3.w * (a3 * b3);
        __builtin_nontemporal_store(r, &o4[j4]);
    }
}

extern "C" void kernel_launch(void* const* d_in, const int* in_sizes, int n_in,
                              void* d_out, int out_size, void* d_ws, size_t ws_size,
                              hipStream_t stream) {
    const float* x       = (const float*)d_in[0];
    const float* weights = (const float*)d_in[1];
    const int*   idx_a   = (const int*)d_in[2];
    const int*   idx_b   = (const int*)d_in[3];
    float* out = (float*)d_out;

    // Workspace layout: Wp (OUT_DIM float4 = 256 KB), Ipk (OUT_DIM uint = 64 KB)
    float4*   Wp  = (float4*)d_ws;
    unsigned* Ipk = (unsigned*)((char*)d_ws + (size_t)OUT_DIM * sizeof(float4));

    prep_kernel<<<(OUT_DIM + 255) / 256, 256, 0, stream>>>(weights, idx_a, idx_b, Wp, Ipk);
    logic_row_kernel<<<BATCH, 1024, 0, stream>>>(x, Wp, (const uint4*)Ipk, out);
}